// Round 4
// baseline (597.762 us; speedup 1.0000x reference)
//
#include <hip/hip_runtime.h>

#define L_HW (128*128)

__device__ __forceinline__ int transp(int p){ return ((p&7)<<3)|(p>>3); }

// ================= K1: in_proj GEMM quarters (+conv+silu for xc) =================
// LDS floats: XIN[64p][68] @0 ; WBUF[64oc][64] @4352 ; XCP[64d][65] @8448 ; XOUT[64p][68] overlays XIN
#define K1_XIN  0
#define K1_WBUF 4352
#define K1_XCP  8448
#define K1_XOUT 0
#define K1_SMEM 12608

__global__ __launch_bounds__(512, 6)
void k1_gemm(const float* __restrict__ x,
             const float* __restrict__ in_proj_w,
             const float* __restrict__ conv_w,
             const float* __restrict__ conv_b,
             float* __restrict__ xct_g,   // [win][64p][128d]
             float* __restrict__ z_g)     // [win][128d][64p]
{
    __shared__ float sm[K1_SMEM];
    const int t = threadIdx.x;
    const int win = blockIdx.x >> 2, q = blockIdx.x & 3;
    const int b = win >> 8, ih = (win >> 4) & 15, iw = win & 15;
    const float* xwin = x + ((size_t)b*64)*L_HW + ih*8*128 + iw*8;

    // stage XIN[p][ch] stride 68
    {
        const int ch = t >> 3, r = t & 7;
        const float* src = xwin + (size_t)ch*L_HW + r*128;
        float4 v0 = *(const float4*)(src);
        float4 v1 = *(const float4*)(src + 4);
        float* dst = sm + K1_XIN + ch;
        const int p0 = r*8;
        dst[(p0+0)*68]=v0.x; dst[(p0+1)*68]=v0.y; dst[(p0+2)*68]=v0.z; dst[(p0+3)*68]=v0.w;
        dst[(p0+4)*68]=v1.x; dst[(p0+5)*68]=v1.y; dst[(p0+6)*68]=v1.z; dst[(p0+7)*68]=v1.w;
    }
    // stage WBUF rows q*64 .. q*64+63
    {
        const float* wsrc = in_proj_w + q*4096;
        *(float4*)(sm + K1_WBUF + t*4)        = *(const float4*)(wsrc + t*4);
        *(float4*)(sm + K1_WBUF + (t+512)*4)  = *(const float4*)(wsrc + (t+512)*4);
    }
    __syncthreads();

    const int p = t & 63, og = t >> 6;
    float acc[8] = {0,0,0,0,0,0,0,0};
    #pragma unroll
    for (int chq = 0; chq < 16; ++chq) {
        float4 xv = *(const float4*)(sm + K1_XIN + p*68 + chq*4);
        #pragma unroll
        for (int j = 0; j < 8; ++j) {
            float4 wv = *(const float4*)(sm + K1_WBUF + (og*8+j)*64 + chq*4);
            acc[j] += xv.x*wv.x + xv.y*wv.y + xv.z*wv.z + xv.w*wv.w;
        }
    }

    if (q >= 2) {   // z quarters: store and done
        float* zw = z_g + (size_t)win*8192 + ((q-2)*64)*64 + p;
        #pragma unroll
        for (int j = 0; j < 8; ++j)
            zw[(og*8+j)*64] = acc[j];
        return;
    }

    // xc quarters: park in XCP[dloc][65]
    #pragma unroll
    for (int j = 0; j < 8; ++j)
        sm[K1_XCP + (og*8+j)*65 + p] = acc[j];
    __syncthreads();

    // depthwise 3x3 conv + silu -> XOUT[p][68]
    {
        const int dloc = t & 63, qq = t >> 6;
        const int dg = q*64 + dloc;
        float cw[9];
        #pragma unroll
        for (int i = 0; i < 9; ++i) cw[i] = conv_w[dg*9 + i];
        const float cb = conv_b[dg];
        #pragma unroll
        for (int jj = 0; jj < 8; ++jj) {
            const int px = qq*8 + jj;
            const int r = px >> 3, c = px & 7;
            float a = cb;
            #pragma unroll
            for (int ki = 0; ki < 3; ++ki) {
                const int rr = r + ki - 1;
                if (rr < 0 || rr > 7) continue;
                #pragma unroll
                for (int kj = 0; kj < 3; ++kj) {
                    const int cc = c + kj - 1;
                    if (cc < 0 || cc > 7) continue;
                    a += sm[K1_XCP + dloc*65 + rr*8 + cc] * cw[ki*3+kj];
                }
            }
            sm[K1_XOUT + px*68 + dloc] = a / (1.f + __expf(-a));
        }
    }
    __syncthreads();

    // store xct (coalesced)
    {
        float* dst = xct_g + (size_t)win*8192 + q*64;
        #pragma unroll
        for (int i = 0; i < 2; ++i) {
            const int idx4 = i*512 + t;
            const int pp = idx4 >> 4, dg = idx4 & 15;
            float4 v = *(const float4*)(sm + K1_XOUT + pp*68 + dg*4);
            *(float4*)(dst + pp*128 + dg*4) = v;
        }
    }
}

// ================= K2: x_proj GEMM, one (win,k) per block =================
#define K2_SMEM 4096   // XT[64p][64] granule-swizzled

__global__ __launch_bounds__(256, 8)
void k2_xproj(const float* __restrict__ xct_g,
              const float* __restrict__ x_proj_w,
              float* __restrict__ xdbl_g)   // [win][4k][64l][36]
{
    __shared__ float sm[K2_SMEM];
    const int t = threadIdx.x;
    const int win = blockIdx.x >> 2, k = blockIdx.x & 3;
    const int p = t & 63, jg = t >> 6;
    float acc[9] = {0,0,0,0,0,0,0,0,0};

    for (int h = 0; h < 2; ++h) {
        __syncthreads();
        #pragma unroll
        for (int i = 0; i < 4; ++i) {
            const int idx4 = i*256 + t;
            const int pp = idx4 >> 4, dg = idx4 & 15;
            float4 v = *(const float4*)(xct_g + (size_t)win*8192 + pp*128 + h*64 + dg*4);
            *(float4*)(sm + pp*64 + ((dg ^ (pp&7))<<2)) = v;
        }
        __syncthreads();
        const float* wb = x_proj_w + (k*36 + jg*9)*128 + h*64;
        #pragma unroll
        for (int dg = 0; dg < 16; ++dg) {
            float4 xv = *(const float4*)(sm + p*64 + ((dg ^ (p&7))<<2));
            #pragma unroll
            for (int jj = 0; jj < 9; ++jj) {
                float4 wv = *(const float4*)(wb + jj*128 + dg*4);
                acc[jj] += xv.x*wv.x + xv.y*wv.y + xv.z*wv.z + xv.w*wv.w;
            }
        }
    }

    const int l = (k==0) ? p : (k==1) ? transp(p) : (k==2) ? (63-p) : (63 - transp(p));
    float* dst = xdbl_g + ((size_t)((size_t)win*4 + k)*64 + l)*36 + jg*9;
    #pragma unroll
    for (int jj = 0; jj < 9; ++jj) dst[jj] = acc[jj];
}

// ================= K3: scan (state-split) + merge + LN + gate + out_proj =================
#define K3_XD 0        // [4k][64l][36] = 9216
#define K3_YM 9216     // [128d][65]    = 8320
#define K3_MU 17536
#define K3_RS 17600
#define K3_SMEM 17664

__global__ __launch_bounds__(1024, 8)
void k3_scan(const float* __restrict__ xct_g,
             const float* __restrict__ z_g,
             const float* __restrict__ xdbl_g,
             const float* __restrict__ dt_projs_w,
             const float* __restrict__ dt_projs_b,
             const float* __restrict__ A_logs,
             const float* __restrict__ Ds,
             const float* __restrict__ ln_g,
             const float* __restrict__ ln_b,
             const float* __restrict__ out_proj_w,
             float* __restrict__ out)
{
    __shared__ float sm[K3_SMEM];
    const int t = threadIdx.x;
    const int win = blockIdx.x;

    // stage xdbl into LDS; zero YM
    #pragma unroll
    for (int i = 0; i < 3; ++i) {
        const int idx4 = i*1024 + t;
        if (idx4 < 2304) {
            float4 v = *(const float4*)(xdbl_g + (size_t)win*9216 + idx4*4);
            *(float4*)(sm + K3_XD + idx4*4) = v;
        }
    }
    for (int i = t; i < 8320; i += 1024) sm[K3_YM + i] = 0.f;
    __syncthreads();

    // ---- scan: thread = (s-half, k, d) ----
    {
        const int sh = t >> 9, k = (t >> 7) & 3, d = t & 127;
        const int kd = k*128 + d, s0 = sh*8;
        const float A0 = -__expf(A_logs[kd*16]);
        bool fast = true;
        #pragma unroll
        for (int si = 0; si < 8; ++si) {
            float a = -__expf(A_logs[kd*16 + s0 + si]);
            fast = fast && (fabsf(a - (float)(s0+si+1)*A0) <= 1e-4f * fabsf(a));
        }
        const float4 wv = *(const float4*)(dt_projs_w + kd*4);
        const float dtb = dt_projs_b[kd];
        const float Dve = sh ? 0.f : Ds[kd];
        float h0=0,h1=0,h2=0,h3=0,h4=0,h5=0,h6=0,h7=0;
        const float* XDk = sm + K3_XD + k*2304;
        const float* ub = xct_g + (size_t)win*8192 + d;

        if (fast) {
            for (int l = 0; l < 64; ++l) {
                const float* row = XDk + l*36;
                float4 d4 = *(const float4*)(row);
                float4 B0 = *(const float4*)(row + 4 + s0);
                float4 B1 = *(const float4*)(row + 8 + s0);
                float4 C0 = *(const float4*)(row + 20 + s0);
                float4 C1 = *(const float4*)(row + 24 + s0);
                float dtraw = dtb + wv.x*d4.x + wv.y*d4.y + wv.z*d4.z + wv.w*d4.w;
                float dt = (dtraw > 20.f) ? dtraw : __logf(1.f + __expf(dtraw));
                const int lr = 63 - l;
                const int p = (k==0)?l : (k==1)?transp(l) : (k==2)?lr : transp(lr);
                const float u = ub[p*128];
                const float dtu = dt * u;
                float r1 = __expf(dt * A0);
                float r2 = r1*r1, r4 = r2*r2, r8 = r4*r4;
                float e1=r1, e2=r2, e3=r2*r1, e4=r4, e5=r4*r1, e6=r4*r2, e7=r4*r2*r1, e8=r8;
                if (sh) { e1*=r8; e2*=r8; e3*=r8; e4*=r8; e5*=r8; e6*=r8; e7*=r8; e8=r8*r8; }
                h0 = h0*e1 + dtu*B0.x;  h1 = h1*e2 + dtu*B0.y;
                h2 = h2*e3 + dtu*B0.z;  h3 = h3*e4 + dtu*B0.w;
                h4 = h4*e5 + dtu*B1.x;  h5 = h5*e6 + dtu*B1.y;
                h6 = h6*e7 + dtu*B1.z;  h7 = h7*e8 + dtu*B1.w;
                float ya = h0*C0.x + h1*C0.y;  ya += h2*C0.z;  ya += h3*C0.w;
                float yb = h4*C1.x + h5*C1.y;  yb += h6*C1.z;  yb += h7*C1.w;
                atomicAdd(&sm[K3_YM + d*65 + p], ya + yb + Dve*u);
            }
        } else {
            float Aq[8];
            #pragma unroll
            for (int si = 0; si < 8; ++si) Aq[si] = -__expf(A_logs[kd*16 + s0 + si]);
            for (int l = 0; l < 64; ++l) {
                const float* row = XDk + l*36;
                float4 d4 = *(const float4*)(row);
                float4 B0 = *(const float4*)(row + 4 + s0);
                float4 B1 = *(const float4*)(row + 8 + s0);
                float4 C0 = *(const float4*)(row + 20 + s0);
                float4 C1 = *(const float4*)(row + 24 + s0);
                float dtraw = dtb + wv.x*d4.x + wv.y*d4.y + wv.z*d4.z + wv.w*d4.w;
                float dt = (dtraw > 20.f) ? dtraw : __logf(1.f + __expf(dtraw));
                const int lr = 63 - l;
                const int p = (k==0)?l : (k==1)?transp(l) : (k==2)?lr : transp(lr);
                const float u = ub[p*128];
                const float dtu = dt * u;
                h0 = h0*__expf(dt*Aq[0]) + dtu*B0.x;  h1 = h1*__expf(dt*Aq[1]) + dtu*B0.y;
                h2 = h2*__expf(dt*Aq[2]) + dtu*B0.z;  h3 = h3*__expf(dt*Aq[3]) + dtu*B0.w;
                h4 = h4*__expf(dt*Aq[4]) + dtu*B1.x;  h5 = h5*__expf(dt*Aq[5]) + dtu*B1.y;
                h6 = h6*__expf(dt*Aq[6]) + dtu*B1.z;  h7 = h7*__expf(dt*Aq[7]) + dtu*B1.w;
                float ya = h0*C0.x + h1*C0.y;  ya += h2*C0.z;  ya += h3*C0.w;
                float yb = h4*C1.x + h5*C1.y;  yb += h6*C1.z;  yb += h7*C1.w;
                atomicAdd(&sm[K3_YM + d*65 + p], ya + yb + Dve*u);
            }
        }
    }
    __syncthreads();

    // ---- LN stats: 16 lanes per pixel ----
    {
        const int px = t >> 4, j = t & 15;
        float s1 = 0.f, s2 = 0.f;
        #pragma unroll
        for (int i = 0; i < 8; ++i) {
            float v = sm[K3_YM + (j*8 + i)*65 + px];
            s1 += v; s2 += v*v;
        }
        s1 += __shfl_xor(s1,1); s2 += __shfl_xor(s2,1);
        s1 += __shfl_xor(s1,2); s2 += __shfl_xor(s2,2);
        s1 += __shfl_xor(s1,4); s2 += __shfl_xor(s2,4);
        s1 += __shfl_xor(s1,8); s2 += __shfl_xor(s2,8);
        if (j == 0) {
            float mu  = s1 * 0.0078125f;
            float var = s2 * 0.0078125f - mu*mu;
            sm[K3_MU + px] = mu;
            sm[K3_RS + px] = rsqrtf(var + 1e-5f);
        }
    }
    __syncthreads();

    // ---- yhat = LN(y) * silu(z), in place ----
    {
        const int p = t & 63, dblk = (t >> 6) * 8;
        const float mu = sm[K3_MU + p], rs = sm[K3_RS + p];
        const float* zb = z_g + (size_t)win*8192 + p;
        #pragma unroll
        for (int i = 0; i < 8; ++i) {
            const int d = dblk + i;
            float yv = sm[K3_YM + d*65 + p];
            float yh = (yv - mu)*rs*ln_g[d] + ln_b[d];
            float zv = zb[d*64];
            sm[K3_YM + d*65 + p] = yh * (zv / (1.f + __expf(-zv)));
        }
    }
    __syncthreads();

    // ---- out_proj: thread = (p, m-quad); 1024 threads cover 64p x 16 quads ----
    {
        const int p = t & 63, m0 = (t >> 6) * 4;   // m0 in 0..60
        float acc[4] = {0,0,0,0};
        #pragma unroll 4
        for (int dq = 0; dq < 32; ++dq) {
            float y0 = sm[K3_YM + (dq*4+0)*65 + p];
            float y1 = sm[K3_YM + (dq*4+1)*65 + p];
            float y2 = sm[K3_YM + (dq*4+2)*65 + p];
            float y3 = sm[K3_YM + (dq*4+3)*65 + p];
            #pragma unroll
            for (int j = 0; j < 4; ++j) {
                float4 wq = *(const float4*)(out_proj_w + (m0+j)*128 + dq*4);
                acc[j] += y0*wq.x + y1*wq.y + y2*wq.z + y3*wq.w;
            }
        }
        const int b = win >> 8, ih = (win>>4)&15, iw = win&15;
        float* op = out + ((size_t)b*64)*L_HW + (ih*8 + (p>>3))*128 + iw*8 + (p&7);
        #pragma unroll
        for (int j = 0; j < 4; ++j)
            op[(size_t)(m0+j)*L_HW] = acc[j];
    }
}

extern "C" void kernel_launch(void* const* d_in, const int* in_sizes, int n_in,
                              void* d_out, int out_size, void* d_ws, size_t ws_size,
                              hipStream_t stream) {
    const float* x          = (const float*)d_in[0];
    const float* in_proj_w  = (const float*)d_in[1];
    const float* conv_w     = (const float*)d_in[2];
    const float* conv_b     = (const float*)d_in[3];
    const float* x_proj_w   = (const float*)d_in[4];
    const float* dt_projs_w = (const float*)d_in[5];
    const float* dt_projs_b = (const float*)d_in[6];
    const float* A_logs     = (const float*)d_in[7];
    const float* Ds         = (const float*)d_in[8];
    const float* ln_g       = (const float*)d_in[9];
    const float* ln_b       = (const float*)d_in[10];
    const float* out_proj_w = (const float*)d_in[11];
    float* out = (float*)d_out;

    float* xct  = (float*)d_ws;            // 512*8192
    float* zb   = xct + 4194304;           // 512*8192
    float* xdbl = zb  + 4194304;           // 512*4*64*36

    k1_gemm<<<dim3(2048), dim3(512), 0, stream>>>(x, in_proj_w, conv_w, conv_b, xct, zb);
    k2_xproj<<<dim3(2048), dim3(256), 0, stream>>>(xct, x_proj_w, xdbl);
    k3_scan<<<dim3(512), dim3(1024), 0, stream>>>(
        xct, zb, xdbl, dt_projs_w, dt_projs_b, A_logs, Ds, ln_g, ln_b,
        out_proj_w, out);
}

// Round 5
// 510.010 us; speedup vs baseline: 1.1721x; 1.1721x over previous
//
#include <hip/hip_runtime.h>

#define L_HW (128*128)

__device__ __forceinline__ int transp(int p){ return ((p&7)<<3)|(p>>3); }

// ================= K1: in_proj GEMM quarters (+conv+silu for xc) =================
// LDS floats: XIN[64p][68] @0 ; WBUF[64oc][64] @4352 ; XCP[64d][65] @8448 ; XOUT[64p][68] overlays XIN
#define K1_XIN  0
#define K1_WBUF 4352
#define K1_XCP  8448
#define K1_XOUT 0
#define K1_SMEM 12608

__global__ __launch_bounds__(512, 6)
void k1_gemm(const float* __restrict__ x,
             const float* __restrict__ in_proj_w,
             const float* __restrict__ conv_w,
             const float* __restrict__ conv_b,
             float* __restrict__ xct_g,   // [win][64p][128d]
             float* __restrict__ z_g)     // [win][128d][64p]
{
    __shared__ float sm[K1_SMEM];
    const int t = threadIdx.x;
    const int win = blockIdx.x >> 2, q = blockIdx.x & 3;
    const int b = win >> 8, ih = (win >> 4) & 15, iw = win & 15;
    const float* xwin = x + ((size_t)b*64)*L_HW + ih*8*128 + iw*8;

    // stage XIN[p][ch] stride 68
    {
        const int ch = t >> 3, r = t & 7;
        const float* src = xwin + (size_t)ch*L_HW + r*128;
        float4 v0 = *(const float4*)(src);
        float4 v1 = *(const float4*)(src + 4);
        float* dst = sm + K1_XIN + ch;
        const int p0 = r*8;
        dst[(p0+0)*68]=v0.x; dst[(p0+1)*68]=v0.y; dst[(p0+2)*68]=v0.z; dst[(p0+3)*68]=v0.w;
        dst[(p0+4)*68]=v1.x; dst[(p0+5)*68]=v1.y; dst[(p0+6)*68]=v1.z; dst[(p0+7)*68]=v1.w;
    }
    // stage WBUF rows q*64 .. q*64+63
    {
        const float* wsrc = in_proj_w + q*4096;
        *(float4*)(sm + K1_WBUF + t*4)        = *(const float4*)(wsrc + t*4);
        *(float4*)(sm + K1_WBUF + (t+512)*4)  = *(const float4*)(wsrc + (t+512)*4);
    }
    __syncthreads();

    const int p = t & 63, og = t >> 6;
    float acc[8] = {0,0,0,0,0,0,0,0};
    #pragma unroll
    for (int chq = 0; chq < 16; ++chq) {
        float4 xv = *(const float4*)(sm + K1_XIN + p*68 + chq*4);
        #pragma unroll
        for (int j = 0; j < 8; ++j) {
            float4 wv = *(const float4*)(sm + K1_WBUF + (og*8+j)*64 + chq*4);
            acc[j] += xv.x*wv.x + xv.y*wv.y + xv.z*wv.z + xv.w*wv.w;
        }
    }

    if (q >= 2) {   // z quarters: store and done
        float* zw = z_g + (size_t)win*8192 + ((q-2)*64)*64 + p;
        #pragma unroll
        for (int j = 0; j < 8; ++j)
            zw[(og*8+j)*64] = acc[j];
        return;
    }

    // xc quarters: park in XCP[dloc][65]
    #pragma unroll
    for (int j = 0; j < 8; ++j)
        sm[K1_XCP + (og*8+j)*65 + p] = acc[j];
    __syncthreads();

    // depthwise 3x3 conv + silu -> XOUT[p][68]
    {
        const int dloc = t & 63, qq = t >> 6;
        const int dg = q*64 + dloc;
        float cw[9];
        #pragma unroll
        for (int i = 0; i < 9; ++i) cw[i] = conv_w[dg*9 + i];
        const float cb = conv_b[dg];
        #pragma unroll
        for (int jj = 0; jj < 8; ++jj) {
            const int px = qq*8 + jj;
            const int r = px >> 3, c = px & 7;
            float a = cb;
            #pragma unroll
            for (int ki = 0; ki < 3; ++ki) {
                const int rr = r + ki - 1;
                if (rr < 0 || rr > 7) continue;
                #pragma unroll
                for (int kj = 0; kj < 3; ++kj) {
                    const int cc = c + kj - 1;
                    if (cc < 0 || cc > 7) continue;
                    a += sm[K1_XCP + dloc*65 + rr*8 + cc] * cw[ki*3+kj];
                }
            }
            sm[K1_XOUT + px*68 + dloc] = a / (1.f + __expf(-a));
        }
    }
    __syncthreads();

    // store xct (coalesced)
    {
        float* dst = xct_g + (size_t)win*8192 + q*64;
        #pragma unroll
        for (int i = 0; i < 2; ++i) {
            const int idx4 = i*512 + t;
            const int pp = idx4 >> 4, dg = idx4 & 15;
            float4 v = *(const float4*)(sm + K1_XOUT + pp*68 + dg*4);
            *(float4*)(dst + pp*128 + dg*4) = v;
        }
    }
}

// ================= K2: x_proj GEMM, one (win,k) per block =================
// LDS: XT[64p][64] swz @0 (4096) ; XDOUT[64l][37] @4096 (2368)
#define K2_XD 4096
#define K2_SMEM 6464

__global__ __launch_bounds__(256, 6)
void k2_xproj(const float* __restrict__ xct_g,
              const float* __restrict__ x_proj_w,
              float* __restrict__ xdbl_g)   // [win][4k][64l][36]
{
    __shared__ float sm[K2_SMEM];
    const int t = threadIdx.x;
    const int win = blockIdx.x >> 2, k = blockIdx.x & 3;
    const int p = t & 63, jg = t >> 6;
    float acc[9] = {0,0,0,0,0,0,0,0,0};

    for (int h = 0; h < 2; ++h) {
        __syncthreads();
        #pragma unroll
        for (int i = 0; i < 4; ++i) {
            const int idx4 = i*256 + t;
            const int pp = idx4 >> 4, dg = idx4 & 15;
            float4 v = *(const float4*)(xct_g + (size_t)win*8192 + pp*128 + h*64 + dg*4);
            *(float4*)(sm + pp*64 + ((dg ^ (pp&7))<<2)) = v;
        }
        __syncthreads();
        const float* wb = x_proj_w + (k*36 + jg*9)*128 + h*64;
        #pragma unroll
        for (int dg = 0; dg < 16; ++dg) {
            float4 xv = *(const float4*)(sm + p*64 + ((dg ^ (p&7))<<2));
            #pragma unroll
            for (int jj = 0; jj < 9; ++jj) {
                float4 wv = *(const float4*)(wb + jj*128 + dg*4);
                acc[jj] += xv.x*wv.x + xv.y*wv.y + xv.z*wv.z + xv.w*wv.w;
            }
        }
    }
    __syncthreads();

    // scatter into LDS in scan order (pad-37 rows)
    {
        const int l = (k==0) ? p : (k==1) ? transp(p) : (k==2) ? (63-p) : (63 - transp(p));
        #pragma unroll
        for (int jj = 0; jj < 9; ++jj)
            sm[K2_XD + l*37 + jg*9 + jj] = acc[jj];
    }
    __syncthreads();

    // coalesced linear store: [64l][36]
    {
        float* dst = xdbl_g + ((size_t)win*4 + k)*2304;
        #pragma unroll
        for (int i = 0; i < 9; ++i) {
            const int idx = i*256 + t;
            const int l2 = idx / 36, c = idx - l2*36;
            dst[idx] = sm[K2_XD + l2*37 + c];
        }
    }
}

// ================= K3: scan (state-split) + merge + LN + gate + out_proj =================
#define K3_XD 0        // [4k][64l][36] = 9216
#define K3_YM 9216     // [128d][65]    = 8320
#define K3_MU 17536
#define K3_RS 17600
#define K3_SMEM 17664

__global__ __launch_bounds__(1024, 8)
void k3_scan(const float* __restrict__ xct_g,
             const float* __restrict__ z_g,
             const float* __restrict__ xdbl_g,
             const float* __restrict__ dt_projs_w,
             const float* __restrict__ dt_projs_b,
             const float* __restrict__ A_logs,
             const float* __restrict__ Ds,
             const float* __restrict__ ln_g,
             const float* __restrict__ ln_b,
             const float* __restrict__ out_proj_w,
             float* __restrict__ out)
{
    __shared__ float sm[K3_SMEM];
    const int t = threadIdx.x;
    const int win = blockIdx.x;

    // stage xdbl into LDS; zero YM
    #pragma unroll
    for (int i = 0; i < 3; ++i) {
        const int idx4 = i*1024 + t;
        if (idx4 < 2304) {
            float4 v = *(const float4*)(xdbl_g + (size_t)win*9216 + idx4*4);
            *(float4*)(sm + K3_XD + idx4*4) = v;
        }
    }
    for (int i = t; i < 8320; i += 1024) sm[K3_YM + i] = 0.f;
    __syncthreads();

    // ---- scan: thread = (s-half, k, d); sh=1 delays its merge-add one step ----
    {
        const int sh = t >> 9, k = (t >> 7) & 3, d = t & 127;
        const int kd = k*128 + d, s0 = sh*8;
        const float A0 = -__expf(A_logs[kd*16]);
        bool fast = true;
        #pragma unroll
        for (int si = 0; si < 8; ++si) {
            float a = -__expf(A_logs[kd*16 + s0 + si]);
            fast = fast && (fabsf(a - (float)(s0+si+1)*A0) <= 1e-4f * fabsf(a));
        }
        const float4 wv = *(const float4*)(dt_projs_w + kd*4);
        const float dtb = dt_projs_b[kd];
        const float Dve = sh ? 0.f : Ds[kd];
        float h0=0,h1=0,h2=0,h3=0,h4=0,h5=0,h6=0,h7=0;
        float ydel = 0.f; int pdel = 0;
        const float* XDk = sm + K3_XD + k*2304;
        const float* ub = xct_g + (size_t)win*8192 + d;

        if (fast) {
            for (int l = 0; l < 64; ++l) {
                const float* row = XDk + l*36;
                float4 d4 = *(const float4*)(row);
                float4 B0 = *(const float4*)(row + 4 + s0);
                float4 B1 = *(const float4*)(row + 8 + s0);
                float4 C0 = *(const float4*)(row + 20 + s0);
                float4 C1 = *(const float4*)(row + 24 + s0);
                float dtraw = dtb + wv.x*d4.x + wv.y*d4.y + wv.z*d4.z + wv.w*d4.w;
                float dt = (dtraw > 20.f) ? dtraw : __logf(1.f + __expf(dtraw));
                const int lr = 63 - l;
                const int p = (k==0)?l : (k==1)?transp(l) : (k==2)?lr : transp(lr);
                const float u = ub[p*128];
                const float dtu = dt * u;
                float r1 = __expf(dt * A0);
                float r2 = r1*r1, r4 = r2*r2, r8 = r4*r4;
                float e1=r1, e2=r2, e3=r2*r1, e4=r4, e5=r4*r1, e6=r4*r2, e7=r4*r2*r1, e8=r8;
                if (sh) { e1*=r8; e2*=r8; e3*=r8; e4*=r8; e5*=r8; e6*=r8; e7*=r8; e8=r8*r8; }
                h0 = h0*e1 + dtu*B0.x;  h1 = h1*e2 + dtu*B0.y;
                h2 = h2*e3 + dtu*B0.z;  h3 = h3*e4 + dtu*B0.w;
                h4 = h4*e5 + dtu*B1.x;  h5 = h5*e6 + dtu*B1.y;
                h6 = h6*e7 + dtu*B1.z;  h7 = h7*e8 + dtu*B1.w;
                float ya = h0*C0.x + h1*C0.y;  ya += h2*C0.z;  ya += h3*C0.w;
                float yb = h4*C1.x + h5*C1.y;  yb += h6*C1.z;  yb += h7*C1.w;
                if (sh) {
                    if (l) atomicAdd(&sm[K3_YM + d*65 + pdel], ydel);
                    ydel = ya + yb; pdel = p;
                } else {
                    atomicAdd(&sm[K3_YM + d*65 + p], ya + yb + Dve*u);
                }
            }
        } else {
            float Aq[8];
            #pragma unroll
            for (int si = 0; si < 8; ++si) Aq[si] = -__expf(A_logs[kd*16 + s0 + si]);
            for (int l = 0; l < 64; ++l) {
                const float* row = XDk + l*36;
                float4 d4 = *(const float4*)(row);
                float4 B0 = *(const float4*)(row + 4 + s0);
                float4 B1 = *(const float4*)(row + 8 + s0);
                float4 C0 = *(const float4*)(row + 20 + s0);
                float4 C1 = *(const float4*)(row + 24 + s0);
                float dtraw = dtb + wv.x*d4.x + wv.y*d4.y + wv.z*d4.z + wv.w*d4.w;
                float dt = (dtraw > 20.f) ? dtraw : __logf(1.f + __expf(dtraw));
                const int lr = 63 - l;
                const int p = (k==0)?l : (k==1)?transp(l) : (k==2)?lr : transp(lr);
                const float u = ub[p*128];
                const float dtu = dt * u;
                h0 = h0*__expf(dt*Aq[0]) + dtu*B0.x;  h1 = h1*__expf(dt*Aq[1]) + dtu*B0.y;
                h2 = h2*__expf(dt*Aq[2]) + dtu*B0.z;  h3 = h3*__expf(dt*Aq[3]) + dtu*B0.w;
                h4 = h4*__expf(dt*Aq[4]) + dtu*B1.x;  h5 = h5*__expf(dt*Aq[5]) + dtu*B1.y;
                h6 = h6*__expf(dt*Aq[6]) + dtu*B1.z;  h7 = h7*__expf(dt*Aq[7]) + dtu*B1.w;
                float ya = h0*C0.x + h1*C0.y;  ya += h2*C0.z;  ya += h3*C0.w;
                float yb = h4*C1.x + h5*C1.y;  yb += h6*C1.z;  yb += h7*C1.w;
                if (sh) {
                    if (l) atomicAdd(&sm[K3_YM + d*65 + pdel], ydel);
                    ydel = ya + yb; pdel = p;
                } else {
                    atomicAdd(&sm[K3_YM + d*65 + p], ya + yb + Dve*u);
                }
            }
        }
        if (sh) atomicAdd(&sm[K3_YM + d*65 + pdel], ydel);
    }
    __syncthreads();

    // ---- LN stats: 16 lanes per pixel ----
    {
        const int px = t >> 4, j = t & 15;
        float s1 = 0.f, s2 = 0.f;
        #pragma unroll
        for (int i = 0; i < 8; ++i) {
            float v = sm[K3_YM + (j*8 + i)*65 + px];
            s1 += v; s2 += v*v;
        }
        s1 += __shfl_xor(s1,1); s2 += __shfl_xor(s2,1);
        s1 += __shfl_xor(s1,2); s2 += __shfl_xor(s2,2);
        s1 += __shfl_xor(s1,4); s2 += __shfl_xor(s2,4);
        s1 += __shfl_xor(s1,8); s2 += __shfl_xor(s2,8);
        if (j == 0) {
            float mu  = s1 * 0.0078125f;
            float var = s2 * 0.0078125f - mu*mu;
            sm[K3_MU + px] = mu;
            sm[K3_RS + px] = rsqrtf(var + 1e-5f);
        }
    }
    __syncthreads();

    // ---- yhat = LN(y) * silu(z), in place ----
    {
        const int p = t & 63, dblk = (t >> 6) * 8;
        const float mu = sm[K3_MU + p], rs = sm[K3_RS + p];
        const float* zb = z_g + (size_t)win*8192 + p;
        #pragma unroll
        for (int i = 0; i < 8; ++i) {
            const int d = dblk + i;
            float yv = sm[K3_YM + d*65 + p];
            float yh = (yv - mu)*rs*ln_g[d] + ln_b[d];
            float zv = zb[d*64];
            sm[K3_YM + d*65 + p] = yh * (zv / (1.f + __expf(-zv)));
        }
    }
    __syncthreads();

    // ---- out_proj: thread = (p, m-quad); 1024 threads cover 64p x 16 quads ----
    {
        const int p = t & 63, m0 = (t >> 6) * 4;   // m0 in 0..60
        float acc[4] = {0,0,0,0};
        #pragma unroll 4
        for (int dq = 0; dq < 32; ++dq) {
            float y0 = sm[K3_YM + (dq*4+0)*65 + p];
            float y1 = sm[K3_YM + (dq*4+1)*65 + p];
            float y2 = sm[K3_YM + (dq*4+2)*65 + p];
            float y3 = sm[K3_YM + (dq*4+3)*65 + p];
            #pragma unroll
            for (int j = 0; j < 4; ++j) {
                float4 wq = *(const float4*)(out_proj_w + (m0+j)*128 + dq*4);
                acc[j] += y0*wq.x + y1*wq.y + y2*wq.z + y3*wq.w;
            }
        }
        const int b = win >> 8, ih = (win>>4)&15, iw = win&15;
        float* op = out + ((size_t)b*64)*L_HW + (ih*8 + (p>>3))*128 + iw*8 + (p&7);
        #pragma unroll
        for (int j = 0; j < 4; ++j)
            op[(size_t)(m0+j)*L_HW] = acc[j];
    }
}

extern "C" void kernel_launch(void* const* d_in, const int* in_sizes, int n_in,
                              void* d_out, int out_size, void* d_ws, size_t ws_size,
                              hipStream_t stream) {
    const float* x          = (const float*)d_in[0];
    const float* in_proj_w  = (const float*)d_in[1];
    const float* conv_w     = (const float*)d_in[2];
    const float* conv_b     = (const float*)d_in[3];
    const float* x_proj_w   = (const float*)d_in[4];
    const float* dt_projs_w = (const float*)d_in[5];
    const float* dt_projs_b = (const float*)d_in[6];
    const float* A_logs     = (const float*)d_in[7];
    const float* Ds         = (const float*)d_in[8];
    const float* ln_g       = (const float*)d_in[9];
    const float* ln_b       = (const float*)d_in[10];
    const float* out_proj_w = (const float*)d_in[11];
    float* out = (float*)d_out;

    float* xct  = (float*)d_ws;            // 512*8192
    float* zb   = xct + 4194304;           // 512*8192
    float* xdbl = zb  + 4194304;           // 512*4*64*36

    k1_gemm<<<dim3(2048), dim3(512), 0, stream>>>(x, in_proj_w, conv_w, conv_b, xct, zb);
    k2_xproj<<<dim3(2048), dim3(256), 0, stream>>>(xct, x_proj_w, xdbl);
    k3_scan<<<dim3(512), dim3(1024), 0, stream>>>(
        xct, zb, xdbl, dt_projs_w, dt_projs_b, A_logs, Ds, ln_g, ln_b,
        out_proj_w, out);
}